// Round 14
// baseline (582.941 us; speedup 1.0000x reference)
//
#include <hip/hip_runtime.h>

// PCLSTM B=512,C=128,H=128,T=512 — round 14: chain cuts on r13.
// 256 wgs x 512 thr (8 waves, 1 wg/CU). Wave w owns ALL 4 gates of units
// [16w,16w+16). i8 h-GEMM: 8 MFMA/wave/step into TWO independent accumulators
// (K-halves un-chained; i32 halves added in EW). EW: NO cross-lane exchange —
// every lane runs the full f/i/u/o chain for batch rb=lane>>5 (redundant x2),
// quadrants 0,2 commit. x-part octet GEMM spread over octet phases 1-4
// (persistent a2 accs; VGPR budget 256 at 2 waves/SIMD). One raw barrier/step.

#define BB 512
#define CC 128
#define HH 128
#define TT 512
#define MB 2
#define XSP 168   // xs row stride (u16)
#define XZP 516   // xz row stride (f32), rows = 2*dt+b
#define OPH 33    // hbuf inner stride (u16)

typedef __attribute__((ext_vector_type(8))) short short8;
typedef __attribute__((ext_vector_type(4))) float f32x4;
typedef __attribute__((ext_vector_type(4))) int v4i;

#define SW 2032.0f
#define SH 127.0f
#define INV_SHW (1.0f / (127.0f * 2032.0f))

__device__ inline unsigned short f2bf(float f) {
    unsigned u = __builtin_bit_cast(unsigned, f);
    u = u + 0x7FFFu + ((u >> 16) & 1u);   // RNE
    return (unsigned short)(u >> 16);
}
__device__ inline float bf2f(unsigned short s) {
    unsigned u = ((unsigned)s) << 16;
    return __builtin_bit_cast(float, u);
}

#define BAR() asm volatile("s_waitcnt lgkmcnt(0)\n\ts_barrier" ::: "memory")

__global__ __launch_bounds__(512, 2) void pclstm_kernel(
    const float* __restrict__ x,
    const float* __restrict__ Wf, const float* __restrict__ bfp,
    const float* __restrict__ Wi, const float* __restrict__ bip,
    const float* __restrict__ Wu, const float* __restrict__ bup,
    const float* __restrict__ Wo, const float* __restrict__ bop,
    float* __restrict__ out)
{
    __shared__ unsigned short xs[64][XSP];          // x bf16: row = 2*(t&31)+b
    __shared__ signed char hs8[2][2][192];          // h i8, double-buffered [p][b][n]
    __shared__ float xz[2][16][XZP];                // x-preacts f32: [buf][2dt+b][un*4+g]
    __shared__ unsigned short hbuf[2][2][HH][OPH];  // h out bf16, 32-step chunks

    const int tid  = threadIdx.x;
    const int lane = tid & 63;
    const int wid  = tid >> 6;            // 0..7
    const int bg0  = blockIdx.x * MB;
    const int l15  = lane & 15;
    const int q    = lane >> 4;           // quadrant
    const int rb   = q >> 1;              // batch row handled by this lane
    const int b4   = lane & 16;           // nonzero for quadrants 1,3
    const int koff = q << 3;              // bf16 K=32 frag k-offset
    const int kq   = q << 4;              // i8 K=64 frag k-offset
    const int un   = wid * 16 + l15;      // owned unit
    const int cq4  = un << 2;             // xz col base (4 gates)

    // ---- weights: wx bf16 (x-part), wh i8 (h-part), all 4 gates of unit un ----
    const float* Wg[4] = {Wf, Wi, Wu, Wo};
    const float* Bg[4] = {bfp, bip, bup, bop};
    short8 wx[4][4];
    v4i wh[4][2];
    float bias[4];
    #pragma unroll
    for (int g = 0; g < 4; ++g) {
        bias[g] = Bg[g][un];
        #pragma unroll
        for (int kt = 0; kt < 4; ++kt) {
            short8 v;
            #pragma unroll
            for (int i = 0; i < 8; ++i)
                v[i] = (short)f2bf(Wg[g][(kt * 32 + koff + i) * HH + un]);
            wx[g][kt] = v;
        }
        #pragma unroll
        for (int kf = 0; kf < 2; ++kf) {
            v4i v;
            #pragma unroll
            for (int d = 0; d < 4; ++d) {
                unsigned pw = 0;
                #pragma unroll
                for (int e = 0; e < 4; ++e) {
                    int qv = (int)__builtin_rintf(
                        Wg[g][(128 + kf * 64 + kq + d * 4 + e) * HH + un] * SW);
                    pw |= ((unsigned)(qv & 255)) << (8 * e);
                }
                v[d] = (int)pw;
            }
            wh[g][kf] = v;
        }
    }

    for (int i = tid; i < 2 * 2 * 192; i += 512)
        ((signed char*)hs8)[i] = 0;

    // ---- stage x chunk [0,16) ----
    {
        int cc = (tid >> 2) & 127, sq0 = tid & 3;
        const float* xp = x + ((size_t)bg0 * CC + cc) * TT + sq0 * 4;
        f32x4 v0 = *(const f32x4*)xp;
        f32x4 v1 = *(const f32x4*)(xp + (size_t)CC * TT);
        #pragma unroll
        for (int j = 0; j < 4; ++j) {
            xs[2 * (sq0 * 4 + j) + 0][cc] = f2bf(v0[j]);
            xs[2 * (sq0 * 4 + j) + 1][cc] = f2bf(v1[j]);
        }
    }
    __syncthreads();

    // persistent x-part accumulators (spread octet GEMM)
    f32x4 a2[4];

    // prologue: full octet GEMM for TB=0
    {
        #pragma unroll
        for (int g = 0; g < 4; ++g)
            a2[g] = (f32x4){bias[g], bias[g], bias[g], bias[g]};
        #pragma unroll
        for (int kt = 0; kt < 4; ++kt) {
            const int s = (l15 >> 1);
            short8 a = *(const short8*)&xs[2 * s + (lane & 1)][kt * 32 + koff];
            #pragma unroll
            for (int g = 0; g < 4; ++g)
                a2[g] = __builtin_amdgcn_mfma_f32_16x16x32_bf16(a, wx[g][kt], a2[g], 0, 0, 0);
        }
        const int r0 = q << 2;            // D row = 2*dt + b
        #pragma unroll
        for (int r = 0; r < 4; ++r) {
            f32x4 vv = {a2[0][r], a2[1][r], a2[2][r], a2[3][r]};
            *(f32x4*)&xz[0][r0 + r][cq4] = vv;
        }
    }
    __syncthreads();

    // xz prefetch for t=0: all 4 gates of own (rb, un)
    f32x4 nx = *(const f32x4*)&xz[0][rb][cq4];

    float cst = 0.0f;                     // c-state (redundant x2; b = rb)
    f32x4 stg0 = {0, 0, 0, 0}, stg1 = {0, 0, 0, 0};
    float* outH = out;
    float* outC = out + (size_t)BB * HH * TT;
    const int scc = (tid >> 2) & 127, sq = tid & 3;
    const int fb = tid >> 8, fn = (tid >> 1) & 127, fh = tid & 1;

    for (int t = 0; t < TT; ++t) {
        const int p = t & 1;
        // ---- h-part MFMA: i8, two INDEPENDENT K-half accumulators ----
        v4i a0 = *(const v4i*)&hs8[p][lane & 1][kq];
        v4i a1 = *(const v4i*)&hs8[p][lane & 1][64 + kq];
        v4i zi0[4], zi1[4];
        const v4i zero4 = {0, 0, 0, 0};
        #pragma unroll
        for (int g = 0; g < 4; ++g) {
            zi0[g] = __builtin_amdgcn_mfma_i32_16x16x64_i8(a0, wh[g][0], zero4, 0, 0, 0);
            zi1[g] = __builtin_amdgcn_mfma_i32_16x16x64_i8(a1, wh[g][1], zero4, 0, 0, 0);
        }

        // ---- service (uniform branches) ----
        const int tm = t & 15;
        if (tm == 0) {
            if (t + 16 < TT) {
                const float* xp = x + ((size_t)bg0 * CC + scc) * TT + (t + 16) + sq * 4;
                stg0 = *(const f32x4*)xp;
                stg1 = *(const f32x4*)(xp + (size_t)CC * TT);
            }
        } else if (tm == 8) {
            if (t + 8 < TT) {
                #pragma unroll
                for (int j = 0; j < 4; ++j) {
                    int sl = (t + 8 + sq * 4 + j) & 31;
                    xs[2 * sl + 0][scc] = f2bf(stg0[j]);
                    xs[2 * sl + 1][scc] = f2bf(stg1[j]);
                }
            }
        }
        // ---- spread x-part octet GEMM: one k-chunk on phases 1..4 ----
        {
            const int ph = t & 7;
            const int TB = (t & ~7) + 8;
            if (ph >= 1 && ph <= 4 && TB < TT) {
                const int kt = ph - 1;
                const int s = (TB + (l15 >> 1)) & 31;
                short8 a = *(const short8*)&xs[2 * s + (lane & 1)][kt * 32 + koff];
                if (kt == 0) {
                    #pragma unroll
                    for (int g = 0; g < 4; ++g)
                        a2[g] = (f32x4){bias[g], bias[g], bias[g], bias[g]};
                }
                #pragma unroll
                for (int g = 0; g < 4; ++g)
                    a2[g] = __builtin_amdgcn_mfma_f32_16x16x32_bf16(a, wx[g][kt], a2[g], 0, 0, 0);
                if (kt == 3) {
                    const int bufw = (TB >> 3) & 1;
                    const int r0 = q << 2;
                    #pragma unroll
                    for (int r = 0; r < 4; ++r) {
                        f32x4 vv = {a2[0][r], a2[1][r], a2[2][r], a2[3][r]};
                        *(f32x4*)&xz[bufw][r0 + r][cq4] = vv;
                    }
                }
            }
        }
        if ((t & 31) == 12 && t >= 32) {
            const int ocp = (t >> 5) - 1;
            const unsigned short* hb = &hbuf[ocp & 1][fb][fn][fh * 16];
            float* op = outH + ((size_t)(bg0 + fb) * HH + fn) * TT + ocp * 32 + fh * 16;
            f32x4 o[4];
            #pragma unroll
            for (int j = 0; j < 16; ++j)
                o[j >> 2][j & 3] = bf2f(hb[j]);
            #pragma unroll
            for (int qq = 0; qq < 4; ++qq)
                *(f32x4*)(op + 4 * qq) = o[qq];
        }

        // ---- EW: full chain per lane for batch rb (no exchange) ----
        {
            f32x4 xa = nx;
            {   // prefetch next step's xz
                const int t1 = t + 1;
                const int buf1 = (t1 >> 3) & 1, dt1 = t1 & 7;
                nx = *(const f32x4*)&xz[buf1][2 * dt1 + rb][cq4];
            }
            int zf = (rb ? zi0[0][1] : zi0[0][0]) + (rb ? zi1[0][1] : zi1[0][0]);
            int zg = (rb ? zi0[1][1] : zi0[1][0]) + (rb ? zi1[1][1] : zi1[1][0]);
            int zu = (rb ? zi0[2][1] : zi0[2][0]) + (rb ? zi1[2][1] : zi1[2][0]);
            int zo = (rb ? zi0[3][1] : zi0[3][0]) + (rb ? zi1[3][1] : zi1[3][0]);
            float vf = (float)zf * INV_SHW + xa[0];
            float vi = (float)zg * INV_SHW + xa[1];
            float vu = (float)zu * INV_SHW + xa[2];
            float vo = (float)zo * INV_SHW + xa[3];
            float fg = __builtin_amdgcn_rcpf(
                           1.0f + __builtin_amdgcn_exp2f(-1.442695041f * vf));
            float ig = __builtin_amdgcn_rcpf(
                           1.0f + __builtin_amdgcn_exp2f(-1.442695041f * vi));
            float ug = 2.0f * __builtin_amdgcn_rcpf(
                           1.0f + __builtin_amdgcn_exp2f(-2.885390082f * vu)) - 1.0f;
            float og = __builtin_amdgcn_rcpf(
                           1.0f + __builtin_amdgcn_exp2f(-1.442695041f * vo));
            cst = cst * fg + ig * ug;
            float th = 2.0f * __builtin_amdgcn_rcpf(
                           1.0f + __builtin_amdgcn_exp2f(-2.885390082f * cst)) - 1.0f;
            float h = og * th;
            if (!b4) {   // quadrants 0,2 commit (b = rb)
                hs8[p ^ 1][rb][un] = (signed char)(int)__builtin_rintf(h * SH);
                hbuf[(t >> 5) & 1][rb][un][t & 31] = f2bf(h);
            }
        }
        BAR();
    }

    // ---- final flush: chunk 15 ----
    {
        const unsigned short* hb = &hbuf[1][fb][fn][fh * 16];
        float* op = outH + ((size_t)(bg0 + fb) * HH + fn) * TT + 480 + fh * 16;
        f32x4 o[4];
        #pragma unroll
        for (int j = 0; j < 16; ++j)
            o[j >> 2][j & 3] = bf2f(hb[j]);
        #pragma unroll
        for (int qq = 0; qq < 4; ++qq)
            *(f32x4*)(op + 4 * qq) = o[qq];
    }
    if (!b4)
        outC[(size_t)(bg0 + rb) * HH + un] = cst;
}

extern "C" void kernel_launch(void* const* d_in, const int* in_sizes, int n_in,
                              void* d_out, int out_size, void* d_ws, size_t ws_size,
                              hipStream_t stream) {
    const float* x  = (const float*)d_in[0];
    const float* Wf = (const float*)d_in[1];
    const float* bf = (const float*)d_in[2];
    const float* Wi = (const float*)d_in[3];
    const float* bi = (const float*)d_in[4];
    const float* Wu = (const float*)d_in[5];
    const float* bu = (const float*)d_in[6];
    const float* Wo = (const float*)d_in[7];
    const float* bo = (const float*)d_in[8];
    float* out = (float*)d_out;

    dim3 grid(BB / MB);   // 256 workgroups, 1 per CU
    dim3 block(512);      // 8 waves
    pclstm_kernel<<<grid, block, 0, stream>>>(x, Wf, bf, Wi, bi, Wu, bu, Wo, bo, out);
}

// Round 15
// 320.881 us; speedup vs baseline: 1.8167x; 1.8167x over previous
//
#include <hip/hip_runtime.h>

// PCLSTM B=512,C=128,H=128,T=512 — round 15: r13 + chain cuts (spill-free).
// 256 wgs x 512 thr (8 waves, 1 wg/CU). Wave w owns ALL 4 gates of units
// [16w,16w+16). i8 h-GEMM: 8 MFMA/wave/step into TWO independent K-half
// accumulators (zero-init; i32 halves added in EW) — MFMA dep chain halved.
// EW: NO cross-lane exchange — A-rows alternate b0/b1, so every quadrant's
// D reg0/reg1 = b0/b1; each lane runs the full f/i/u/o chain for rb=lane>>5
// (redundant x2), quadrants 0,2 commit. Burst x-part octet GEMM (unrolled kt
// — compile-time weight indices, no scratch). One raw barrier/step.

#define BB 512
#define CC 128
#define HH 128
#define TT 512
#define MB 2
#define XSP 168   // xs row stride (u16)
#define XZP 516   // xz row stride (f32), rows = 2*dt+b
#define OPH 33    // hbuf inner stride (u16)

typedef __attribute__((ext_vector_type(8))) short short8;
typedef __attribute__((ext_vector_type(4))) float f32x4;
typedef __attribute__((ext_vector_type(4))) int v4i;

#define SW 2032.0f
#define SH 127.0f
#define INV_SHW (1.0f / (127.0f * 2032.0f))

__device__ inline unsigned short f2bf(float f) {
    unsigned u = __builtin_bit_cast(unsigned, f);
    u = u + 0x7FFFu + ((u >> 16) & 1u);   // RNE
    return (unsigned short)(u >> 16);
}
__device__ inline float bf2f(unsigned short s) {
    unsigned u = ((unsigned)s) << 16;
    return __builtin_bit_cast(float, u);
}

#define BAR() asm volatile("s_waitcnt lgkmcnt(0)\n\ts_barrier" ::: "memory")

__global__ __launch_bounds__(512, 2) void pclstm_kernel(
    const float* __restrict__ x,
    const float* __restrict__ Wf, const float* __restrict__ bfp,
    const float* __restrict__ Wi, const float* __restrict__ bip,
    const float* __restrict__ Wu, const float* __restrict__ bup,
    const float* __restrict__ Wo, const float* __restrict__ bop,
    float* __restrict__ out)
{
    __shared__ unsigned short xs[64][XSP];          // x bf16: row = 2*(t&31)+b
    __shared__ signed char hs8[2][2][192];          // h i8, double-buffered [p][b][n]
    __shared__ float xz[2][16][XZP];                // x-preacts f32: [buf][2dt+b][un*4+g]
    __shared__ unsigned short hbuf[2][2][HH][OPH];  // h out bf16, 32-step chunks

    const int tid  = threadIdx.x;
    const int lane = tid & 63;
    const int wid  = tid >> 6;            // 0..7
    const int bg0  = blockIdx.x * MB;
    const int l15  = lane & 15;
    const int q    = lane >> 4;           // quadrant
    const int rb   = q >> 1;              // batch row handled by this lane
    const int b4   = lane & 16;           // nonzero for quadrants 1,3
    const int koff = q << 3;              // bf16 K=32 frag k-offset
    const int kq   = q << 4;              // i8 K=64 frag k-offset
    const int un   = wid * 16 + l15;      // owned unit
    const int cq4  = un << 2;             // xz col base (4 gates)

    // ---- weights: wx bf16 (x-part), wh i8 (h-part), all 4 gates of unit un ----
    const float* Wg[4] = {Wf, Wi, Wu, Wo};
    const float* Bg[4] = {bfp, bip, bup, bop};
    short8 wx[4][4];
    v4i wh[4][2];
    float bias[4];
    #pragma unroll
    for (int g = 0; g < 4; ++g) {
        bias[g] = Bg[g][un];
        #pragma unroll
        for (int kt = 0; kt < 4; ++kt) {
            short8 v;
            #pragma unroll
            for (int i = 0; i < 8; ++i)
                v[i] = (short)f2bf(Wg[g][(kt * 32 + koff + i) * HH + un]);
            wx[g][kt] = v;
        }
        #pragma unroll
        for (int kf = 0; kf < 2; ++kf) {
            v4i v;
            #pragma unroll
            for (int d = 0; d < 4; ++d) {
                unsigned pw = 0;
                #pragma unroll
                for (int e = 0; e < 4; ++e) {
                    int qv = (int)__builtin_rintf(
                        Wg[g][(128 + kf * 64 + kq + d * 4 + e) * HH + un] * SW);
                    pw |= ((unsigned)(qv & 255)) << (8 * e);
                }
                v[d] = (int)pw;
            }
            wh[g][kf] = v;
        }
    }

    for (int i = tid; i < 2 * 2 * 192; i += 512)
        ((signed char*)hs8)[i] = 0;

    // ---- stage x chunk [0,16) ----
    {
        int cc = (tid >> 2) & 127, sq0 = tid & 3;
        const float* xp = x + ((size_t)bg0 * CC + cc) * TT + sq0 * 4;
        f32x4 v0 = *(const f32x4*)xp;
        f32x4 v1 = *(const f32x4*)(xp + (size_t)CC * TT);
        #pragma unroll
        for (int j = 0; j < 4; ++j) {
            xs[2 * (sq0 * 4 + j) + 0][cc] = f2bf(v0[j]);
            xs[2 * (sq0 * 4 + j) + 1][cc] = f2bf(v1[j]);
        }
    }
    __syncthreads();

    // x-part octet GEMM (bf16): m=16 tile = (8 steps x 2 batch), K=128.
    // Fully unrolled kt -> compile-time wx indices (no scratch).
    auto xzg = [&](int TB) {
        const int buf = (TB >> 3) & 1;
        f32x4 a2[4];
        #pragma unroll
        for (int g = 0; g < 4; ++g)
            a2[g] = (f32x4){bias[g], bias[g], bias[g], bias[g]};
        #pragma unroll
        for (int kt = 0; kt < 4; ++kt) {
            const int s = (TB + (l15 >> 1)) & 31;
            short8 a = *(const short8*)&xs[2 * s + (lane & 1)][kt * 32 + koff];
            #pragma unroll
            for (int g = 0; g < 4; ++g)
                a2[g] = __builtin_amdgcn_mfma_f32_16x16x32_bf16(a, wx[g][kt], a2[g], 0, 0, 0);
        }
        const int r0 = q << 2;              // D row = 2*dt + b
        #pragma unroll
        for (int r = 0; r < 4; ++r) {
            f32x4 vv = {a2[0][r], a2[1][r], a2[2][r], a2[3][r]};
            *(f32x4*)&xz[buf][r0 + r][cq4] = vv;
        }
    };

    xzg(0);
    __syncthreads();

    // xz prefetch for t=0: all 4 gates of own (rb, un)
    f32x4 nx = *(const f32x4*)&xz[0][rb][cq4];

    float cst = 0.0f;                     // c-state (redundant x2; b = rb)
    f32x4 stg0 = {0, 0, 0, 0}, stg1 = {0, 0, 0, 0};
    float* outH = out;
    float* outC = out + (size_t)BB * HH * TT;
    const int scc = (tid >> 2) & 127, sq = tid & 3;
    const int fb = tid >> 8, fn = (tid >> 1) & 127, fh = tid & 1;

    for (int t = 0; t < TT; ++t) {
        const int p = t & 1;
        // ---- h-part MFMA: i8, two INDEPENDENT K-half accumulators ----
        v4i a0 = *(const v4i*)&hs8[p][lane & 1][kq];
        v4i a1 = *(const v4i*)&hs8[p][lane & 1][64 + kq];
        const v4i zero4 = {0, 0, 0, 0};
        v4i zi0[4], zi1[4];
        #pragma unroll
        for (int g = 0; g < 4; ++g) {
            zi0[g] = __builtin_amdgcn_mfma_i32_16x16x64_i8(a0, wh[g][0], zero4, 0, 0, 0);
            zi1[g] = __builtin_amdgcn_mfma_i32_16x16x64_i8(a1, wh[g][1], zero4, 0, 0, 0);
        }

        // ---- service (uniform branches) ----
        const int tm = t & 15;
        if (tm == 0) {
            if (t + 16 < TT) {
                const float* xp = x + ((size_t)bg0 * CC + scc) * TT + (t + 16) + sq * 4;
                stg0 = *(const f32x4*)xp;
                stg1 = *(const f32x4*)(xp + (size_t)CC * TT);
            }
        } else if (tm == 8) {
            if (t + 8 < TT) {
                #pragma unroll
                for (int j = 0; j < 4; ++j) {
                    int sl = (t + 8 + sq * 4 + j) & 31;
                    xs[2 * sl + 0][scc] = f2bf(stg0[j]);
                    xs[2 * sl + 1][scc] = f2bf(stg1[j]);
                }
            }
        }
        if ((t & 7) == 1 && t + 7 < TT)
            xzg(t + 7);
        if ((t & 31) == 12 && t >= 32) {
            const int ocp = (t >> 5) - 1;
            const unsigned short* hb = &hbuf[ocp & 1][fb][fn][fh * 16];
            float* op = outH + ((size_t)(bg0 + fb) * HH + fn) * TT + ocp * 32 + fh * 16;
            f32x4 o[4];
            #pragma unroll
            for (int j = 0; j < 16; ++j)
                o[j >> 2][j & 3] = bf2f(hb[j]);
            #pragma unroll
            for (int qq = 0; qq < 4; ++qq)
                *(f32x4*)(op + 4 * qq) = o[qq];
        }

        // ---- EW: full chain per lane for batch rb (no exchange) ----
        {
            f32x4 xa = nx;
            {   // prefetch next step's xz
                const int t1 = t + 1;
                const int buf1 = (t1 >> 3) & 1, dt1 = t1 & 7;
                nx = *(const f32x4*)&xz[buf1][2 * dt1 + rb][cq4];
            }
            // D reg0 = b0, reg1 = b1 in every quadrant (A rows alternate b0/b1)
            int zf = (rb ? zi0[0][1] : zi0[0][0]) + (rb ? zi1[0][1] : zi1[0][0]);
            int zg = (rb ? zi0[1][1] : zi0[1][0]) + (rb ? zi1[1][1] : zi1[1][0]);
            int zu = (rb ? zi0[2][1] : zi0[2][0]) + (rb ? zi1[2][1] : zi1[2][0]);
            int zo = (rb ? zi0[3][1] : zi0[3][0]) + (rb ? zi1[3][1] : zi1[3][0]);
            float vf = (float)zf * INV_SHW + xa[0];
            float vi = (float)zg * INV_SHW + xa[1];
            float vu = (float)zu * INV_SHW + xa[2];
            float vo = (float)zo * INV_SHW + xa[3];
            float fg = __builtin_amdgcn_rcpf(
                           1.0f + __builtin_amdgcn_exp2f(-1.442695041f * vf));
            float ig = __builtin_amdgcn_rcpf(
                           1.0f + __builtin_amdgcn_exp2f(-1.442695041f * vi));
            float ug = 2.0f * __builtin_amdgcn_rcpf(
                           1.0f + __builtin_amdgcn_exp2f(-2.885390082f * vu)) - 1.0f;
            float og = __builtin_amdgcn_rcpf(
                           1.0f + __builtin_amdgcn_exp2f(-1.442695041f * vo));
            cst = cst * fg + ig * ug;
            float th = 2.0f * __builtin_amdgcn_rcpf(
                           1.0f + __builtin_amdgcn_exp2f(-2.885390082f * cst)) - 1.0f;
            float h = og * th;
            if (!b4) {   // quadrants 0,2 commit (b = rb)
                hs8[p ^ 1][rb][un] = (signed char)(int)__builtin_rintf(h * SH);
                hbuf[(t >> 5) & 1][rb][un][t & 31] = f2bf(h);
            }
        }
        BAR();
    }

    // ---- final flush: chunk 15 ----
    {
        const unsigned short* hb = &hbuf[1][fb][fn][fh * 16];
        float* op = outH + ((size_t)(bg0 + fb) * HH + fn) * TT + 480 + fh * 16;
        f32x4 o[4];
        #pragma unroll
        for (int j = 0; j < 16; ++j)
            o[j >> 2][j & 3] = bf2f(hb[j]);
        #pragma unroll
        for (int qq = 0; qq < 4; ++qq)
            *(f32x4*)(op + 4 * qq) = o[qq];
    }
    if (!b4)
        outC[(size_t)(bg0 + rb) * HH + un] = cst;
}

extern "C" void kernel_launch(void* const* d_in, const int* in_sizes, int n_in,
                              void* d_out, int out_size, void* d_ws, size_t ws_size,
                              hipStream_t stream) {
    const float* x  = (const float*)d_in[0];
    const float* Wf = (const float*)d_in[1];
    const float* bf = (const float*)d_in[2];
    const float* Wi = (const float*)d_in[3];
    const float* bi = (const float*)d_in[4];
    const float* Wu = (const float*)d_in[5];
    const float* bu = (const float*)d_in[6];
    const float* Wo = (const float*)d_in[7];
    const float* bo = (const float*)d_in[8];
    float* out = (float*)d_out;

    dim3 grid(BB / MB);   // 256 workgroups, 1 per CU
    dim3 block(512);      // 8 waves
    pclstm_kernel<<<grid, block, 0, stream>>>(x, Wf, bf, Wi, bi, Wu, bu, Wo, bo, out);
}

// Round 16
// 320.221 us; speedup vs baseline: 1.8204x; 1.0021x over previous
//
#include <hip/hip_runtime.h>

// PCLSTM B=512,C=128,H=128,T=512 — round 16: r10 + unchained MFMA halves
// + conflict-free ew stride. 256 wgs x 512 thr (8 waves, 1 wg/CU). Wave w
// owns ALL 4 gates of units [16w,16w+16). i8 h-GEMM: 8 MFMA/wave/step into
// TWO independent K-half accumulators (i32 halves added in EW) — one fewer
// MFMA-latency link in the serial chain. EW: quadrant q computes gate q's
// activation on all 64 lanes, exchange via ew[8][16][13] LDS (odd stride =
// conflict-free); 32 handler lanes do the c/h update. Burst x-part octet
// GEMM every 8 steps (bf16, unrolled). One raw barrier per step.

#define BB 512
#define CC 128
#define HH 128
#define TT 512
#define MB 2
#define XSP 168   // xs row stride (u16)
#define XZP 516   // xz row stride (f32), rows = 2*dt+b
#define OPH 33    // hbuf inner stride (u16)

typedef __attribute__((ext_vector_type(8))) short short8;
typedef __attribute__((ext_vector_type(4))) float f32x4;
typedef __attribute__((ext_vector_type(4))) int v4i;

#define SW 2032.0f
#define SH 127.0f
#define INV_SHW (1.0f / (127.0f * 2032.0f))

__device__ inline unsigned short f2bf(float f) {
    unsigned u = __builtin_bit_cast(unsigned, f);
    u = u + 0x7FFFu + ((u >> 16) & 1u);   // RNE
    return (unsigned short)(u >> 16);
}
__device__ inline float bf2f(unsigned short s) {
    unsigned u = ((unsigned)s) << 16;
    return __builtin_bit_cast(float, u);
}

#define BAR() asm volatile("s_waitcnt lgkmcnt(0)\n\ts_barrier" ::: "memory")

__global__ __launch_bounds__(512, 2) void pclstm_kernel(
    const float* __restrict__ x,
    const float* __restrict__ Wf, const float* __restrict__ bfp,
    const float* __restrict__ Wi, const float* __restrict__ bip,
    const float* __restrict__ Wu, const float* __restrict__ bup,
    const float* __restrict__ Wo, const float* __restrict__ bop,
    float* __restrict__ out)
{
    __shared__ unsigned short xs[64][XSP];          // x bf16: row = 2*(t&31)+b
    __shared__ signed char hs8[2][2][192];          // h i8, double-buffered [p][b][n]
    __shared__ float xz[2][16][XZP];                // x-preacts f32: [buf][2dt+b][un*4+g]
    __shared__ float ew[8][16][13];                 // act exchange, odd stride
    __shared__ unsigned short hbuf[2][2][HH][OPH];  // h out bf16, 32-step chunks

    const int tid  = threadIdx.x;
    const int lane = tid & 63;
    const int wid  = tid >> 6;            // 0..7
    const int bg0  = blockIdx.x * MB;
    const int l15  = lane & 15;
    const int q    = lane >> 4;           // quadrant = gate handled in EW
    const int koff = q << 3;              // bf16 K=32 frag k-offset
    const int kq   = q << 4;              // i8 K=64 frag k-offset
    const int un   = wid * 16 + l15;      // owned unit
    const int cq4  = (un << 2) + q;       // xz col for own gate

    // act constants: gate q==2 is tanh (=2*sigmoid(2z)-1), others sigmoid
    const float esc = (q == 2) ? -2.885390082f : -1.442695041f;
    const float ym  = (q == 2) ? 2.0f : 1.0f;
    const float yk  = (q == 2) ? -1.0f : 0.0f;

    // ---- weights: wx bf16 (x-part), wh i8 (h-part), all 4 gates of unit un ----
    const float* Wg[4] = {Wf, Wi, Wu, Wo};
    const float* Bg[4] = {bfp, bip, bup, bop};
    short8 wx[4][4];
    v4i wh[4][2];
    float bias[4];
    #pragma unroll
    for (int g = 0; g < 4; ++g) {
        bias[g] = Bg[g][un];
        #pragma unroll
        for (int kt = 0; kt < 4; ++kt) {
            short8 v;
            #pragma unroll
            for (int i = 0; i < 8; ++i)
                v[i] = (short)f2bf(Wg[g][(kt * 32 + koff + i) * HH + un]);
            wx[g][kt] = v;
        }
        #pragma unroll
        for (int kf = 0; kf < 2; ++kf) {
            v4i v;
            #pragma unroll
            for (int d = 0; d < 4; ++d) {
                unsigned pw = 0;
                #pragma unroll
                for (int e = 0; e < 4; ++e) {
                    int qv = (int)__builtin_rintf(
                        Wg[g][(128 + kf * 64 + kq + d * 4 + e) * HH + un] * SW);
                    pw |= ((unsigned)(qv & 255)) << (8 * e);
                }
                v[d] = (int)pw;
            }
            wh[g][kf] = v;
        }
    }

    for (int i = tid; i < 2 * 2 * 192; i += 512)
        ((signed char*)hs8)[i] = 0;

    // ---- stage x chunk [0,16) ----
    {
        int cc = (tid >> 2) & 127, sq0 = tid & 3;
        const float* xp = x + ((size_t)bg0 * CC + cc) * TT + sq0 * 4;
        f32x4 v0 = *(const f32x4*)xp;
        f32x4 v1 = *(const f32x4*)(xp + (size_t)CC * TT);
        #pragma unroll
        for (int j = 0; j < 4; ++j) {
            xs[2 * (sq0 * 4 + j) + 0][cc] = f2bf(v0[j]);
            xs[2 * (sq0 * 4 + j) + 1][cc] = f2bf(v1[j]);
        }
    }
    __syncthreads();

    // x-part octet GEMM (bf16): m=16 tile = (8 steps x 2 batch), K=128.
    auto xzg = [&](int TB) {
        const int buf = (TB >> 3) & 1;
        f32x4 a2[4];
        #pragma unroll
        for (int g = 0; g < 4; ++g)
            a2[g] = (f32x4){bias[g], bias[g], bias[g], bias[g]};
        #pragma unroll
        for (int kt = 0; kt < 4; ++kt) {
            const int s = (TB + (l15 >> 1)) & 31;
            short8 a = *(const short8*)&xs[2 * s + (lane & 1)][kt * 32 + koff];
            #pragma unroll
            for (int g = 0; g < 4; ++g)
                a2[g] = __builtin_amdgcn_mfma_f32_16x16x32_bf16(a, wx[g][kt], a2[g], 0, 0, 0);
        }
        const int row0 = q << 2;              // D row = 2*dt + b
        #pragma unroll
        for (int r = 0; r < 4; ++r) {
            f32x4 vv = {a2[0][r], a2[1][r], a2[2][r], a2[3][r]};
            *(f32x4*)&xz[buf][row0 + r][un << 2] = vv;
        }
    };

    xzg(0);
    __syncthreads();

    // xz prefetch for t=0: this lane's gate-q scalar for b0 and b1
    float nxa = xz[0][0][cq4];
    float nxb = xz[0][1][cq4];

    float cst = 0.0f;                     // handler (lane<32) c-state
    f32x4 stg0 = {0, 0, 0, 0}, stg1 = {0, 0, 0, 0};
    float* outH = out;
    float* outC = out + (size_t)BB * HH * TT;
    const int scc = (tid >> 2) & 127, sq = tid & 3;
    const int fb = tid >> 8, fn = (tid >> 1) & 127, fh = tid & 1;

    for (int t = 0; t < TT; ++t) {
        const int p = t & 1;
        // ---- h-part MFMA: i8, two INDEPENDENT K-half accumulators ----
        v4i a0 = *(const v4i*)&hs8[p][lane & 1][kq];
        v4i a1 = *(const v4i*)&hs8[p][lane & 1][64 + kq];
        const v4i zero4 = {0, 0, 0, 0};
        v4i zi[4], zj[4];
        #pragma unroll
        for (int g = 0; g < 4; ++g) {
            zi[g] = __builtin_amdgcn_mfma_i32_16x16x64_i8(a0, wh[g][0], zero4, 0, 0, 0);
            zj[g] = __builtin_amdgcn_mfma_i32_16x16x64_i8(a1, wh[g][1], zero4, 0, 0, 0);
        }

        // ---- service (uniform branches) ----
        const int tm = t & 15;
        if (tm == 0) {
            if (t + 16 < TT) {
                const float* xp = x + ((size_t)bg0 * CC + scc) * TT + (t + 16) + sq * 4;
                stg0 = *(const f32x4*)xp;
                stg1 = *(const f32x4*)(xp + (size_t)CC * TT);
            }
        } else if (tm == 8) {
            if (t + 8 < TT) {
                #pragma unroll
                for (int j = 0; j < 4; ++j) {
                    int sl = (t + 8 + sq * 4 + j) & 31;
                    xs[2 * sl + 0][scc] = f2bf(stg0[j]);
                    xs[2 * sl + 1][scc] = f2bf(stg1[j]);
                }
            }
        }
        if ((t & 7) == 1 && t + 7 < TT)
            xzg(t + 7);
        if ((t & 31) == 12 && t >= 32) {
            const int ocp = (t >> 5) - 1;
            const unsigned short* hb = &hbuf[ocp & 1][fb][fn][fh * 16];
            float* op = outH + ((size_t)(bg0 + fb) * HH + fn) * TT + ocp * 32 + fh * 16;
            f32x4 o[4];
            #pragma unroll
            for (int j = 0; j < 16; ++j)
                o[j >> 2][j & 3] = bf2f(hb[j]);
            #pragma unroll
            for (int qq = 0; qq < 4; ++qq)
                *(f32x4*)(op + 4 * qq) = o[qq];
        }

        // ---- EW: quadrant q computes gate q's activation (all 64 lanes) ----
        {
            float xa = nxa, xb = nxb;
            {   // prefetch next step's xz
                const int t1 = t + 1;
                const int buf1 = (t1 >> 3) & 1, dt1 = t1 & 7;
                nxa = xz[buf1][2 * dt1 + 0][cq4];
                nxb = xz[buf1][2 * dt1 + 1][cq4];
            }
            int zs0 = ((q & 2) ? ((q & 1) ? zi[3][0] : zi[2][0])
                               : ((q & 1) ? zi[1][0] : zi[0][0]))
                    + ((q & 2) ? ((q & 1) ? zj[3][0] : zj[2][0])
                               : ((q & 1) ? zj[1][0] : zj[0][0]));
            int zs1 = ((q & 2) ? ((q & 1) ? zi[3][1] : zi[2][1])
                               : ((q & 1) ? zi[1][1] : zi[0][1]))
                    + ((q & 2) ? ((q & 1) ? zj[3][1] : zj[2][1])
                               : ((q & 1) ? zj[1][1] : zj[0][1]));
            float z0 = (float)zs0 * INV_SHW + xa;
            float z1 = (float)zs1 * INV_SHW + xb;
            float ya = ym * __builtin_amdgcn_rcpf(
                           1.0f + __builtin_amdgcn_exp2f(esc * z0)) + yk;
            float yb = ym * __builtin_amdgcn_rcpf(
                           1.0f + __builtin_amdgcn_exp2f(esc * z1)) + yk;
            ew[wid][l15][q]     = ya;
            ew[wid][l15][4 + q] = yb;
        }
        // handlers: lanes 0-31, (b = lane>>4, unit = un)
        if (lane < 32) {
            const int hbx = lane >> 4;
            f32x4 g4 = *(const f32x4*)&ew[wid][l15][hbx * 4];   // f,i,u,o
            cst = cst * g4[0] + g4[1] * g4[2];
            float th = 2.0f * __builtin_amdgcn_rcpf(
                           1.0f + __builtin_amdgcn_exp2f(-2.885390082f * cst)) - 1.0f;
            float h = g4[3] * th;
            hs8[p ^ 1][hbx][un] = (signed char)(int)__builtin_rintf(h * SH);
            hbuf[(t >> 5) & 1][hbx][un][t & 31] = f2bf(h);
        }
        BAR();
    }

    // ---- final flush: chunk 15 ----
    {
        const unsigned short* hb = &hbuf[1][fb][fn][fh * 16];
        float* op = outH + ((size_t)(bg0 + fb) * HH + fn) * TT + 480 + fh * 16;
        f32x4 o[4];
        #pragma unroll
        for (int j = 0; j < 16; ++j)
            o[j >> 2][j & 3] = bf2f(hb[j]);
        #pragma unroll
        for (int qq = 0; qq < 4; ++qq)
            *(f32x4*)(op + 4 * qq) = o[qq];
    }
    if (lane < 32)
        outC[(size_t)(bg0 + (lane >> 4)) * HH + un] = cst;
}

extern "C" void kernel_launch(void* const* d_in, const int* in_sizes, int n_in,
                              void* d_out, int out_size, void* d_ws, size_t ws_size,
                              hipStream_t stream) {
    const float* x  = (const float*)d_in[0];
    const float* Wf = (const float*)d_in[1];
    const float* bf = (const float*)d_in[2];
    const float* Wi = (const float*)d_in[3];
    const float* bi = (const float*)d_in[4];
    const float* Wu = (const float*)d_in[5];
    const float* bu = (const float*)d_in[6];
    const float* Wo = (const float*)d_in[7];
    const float* bo = (const float*)d_in[8];
    float* out = (float*)d_out;

    dim3 grid(BB / MB);   // 256 workgroups, 1 per CU
    dim3 block(512);      // 8 waves
    pclstm_kernel<<<grid, block, 0, stream>>>(x, Wf, bf, Wi, bi, Wu, bu, Wo, bo, out);
}

// Round 17
// 304.070 us; speedup vs baseline: 1.9171x; 1.0531x over previous
//
#include <hip/hip_runtime.h>

// PCLSTM B=512,C=128,H=128,T=512 — FINAL (round 10 kernel, best measured:
// 304 us, absmax 0.0039). 256 wgs x 512 thr (8 waves, 1 wg/CU). Wave w owns
// ALL 4 gates of units [16w,16w+16). i8 h-GEMM (8 MFMA/wave/step, i32 exact
// acc; W*2032 exact-bounded, h*127). bf16 x-part octet GEMM every 8 steps.
// EW packing: quadrant q computes gate q's activation on ALL 64 lanes
// (trans issue 20->6 per wave), exchanged via per-wave ew[16][12] LDS;
// 32 handler lanes do the c/h update in fp32. h output buffered bf16 in LDS,
// flushed as coalesced float4 every 32 steps. One raw barrier per step
// (lgkmcnt only — vmcnt never drained in the loop).
//
// Session ledger (16 rounds): per-step floor ~660 ns = 330cy MFMA issue +
// ~520cy VALU + ~700cy exposed serial-chain latency (h LDS roundtrip ->
// dependent MFMA -> transcendental chain -> barrier). Latency-bound, not
// pipe-bound: role-split waves, flag-sync, 2 wg/CU, spread-xzg, shfl/
// no-exchange EW, unchained MFMA halves all measured neutral-to-worse.

#define BB 512
#define CC 128
#define HH 128
#define TT 512
#define MB 2
#define XSP 168   // xs row stride (u16)
#define XZP 516   // xz row stride (f32), rows = 2*dt+b
#define OPH 33    // hbuf inner stride (u16)

typedef __attribute__((ext_vector_type(8))) short short8;
typedef __attribute__((ext_vector_type(4))) float f32x4;
typedef __attribute__((ext_vector_type(4))) int v4i;

#define SW 2032.0f
#define SH 127.0f
#define INV_SHW (1.0f / (127.0f * 2032.0f))

__device__ inline unsigned short f2bf(float f) {
    unsigned u = __builtin_bit_cast(unsigned, f);
    u = u + 0x7FFFu + ((u >> 16) & 1u);   // RNE
    return (unsigned short)(u >> 16);
}
__device__ inline float bf2f(unsigned short s) {
    unsigned u = ((unsigned)s) << 16;
    return __builtin_bit_cast(float, u);
}

#define BAR() asm volatile("s_waitcnt lgkmcnt(0)\n\ts_barrier" ::: "memory")

__global__ __launch_bounds__(512, 2) void pclstm_kernel(
    const float* __restrict__ x,
    const float* __restrict__ Wf, const float* __restrict__ bfp,
    const float* __restrict__ Wi, const float* __restrict__ bip,
    const float* __restrict__ Wu, const float* __restrict__ bup,
    const float* __restrict__ Wo, const float* __restrict__ bop,
    float* __restrict__ out)
{
    __shared__ unsigned short xs[64][XSP];          // x bf16: row = 2*(t&31)+b
    __shared__ signed char hs8[2][2][192];          // h i8, double-buffered [p][b][n]
    __shared__ float xz[2][16][XZP];                // x-preacts f32: [buf][2dt+b][un*4+g]
    __shared__ float ew[8][16][12];                 // per-wave act exchange [wid][l15][b*4+g]
    __shared__ unsigned short hbuf[2][MB][HH][OPH]; // h out bf16, 32-step chunks

    const int tid  = threadIdx.x;
    const int lane = tid & 63;
    const int wid  = tid >> 6;            // 0..7
    const int bg0  = blockIdx.x * MB;
    const int l15  = lane & 15;
    const int q    = lane >> 4;           // quadrant = gate handled in EW
    const int koff = q << 3;              // bf16 K=32 frag k-offset
    const int kq   = q << 4;              // i8 K=64 frag k-offset
    const int un   = wid * 16 + l15;      // owned unit

    // act constants: gate q==2 is tanh (=2*sigmoid(2z)-1), others sigmoid
    const float esc = (q == 2) ? -2.885390082f : -1.442695041f;
    const float ym  = (q == 2) ? 2.0f : 1.0f;
    const float yk  = (q == 2) ? -1.0f : 0.0f;

    // ---- weights: wx bf16 (x-part), wh i8 (h-part), all 4 gates of unit un ----
    const float* Wg[4] = {Wf, Wi, Wu, Wo};
    const float* Bg[4] = {bfp, bip, bup, bop};
    short8 wx[4][4];
    v4i wh[4][2];
    float bias[4];
    #pragma unroll
    for (int g = 0; g < 4; ++g) {
        bias[g] = Bg[g][un];
        #pragma unroll
        for (int kt = 0; kt < 4; ++kt) {
            short8 v;
            #pragma unroll
            for (int i = 0; i < 8; ++i)
                v[i] = (short)f2bf(Wg[g][(kt * 32 + koff + i) * HH + un]);
            wx[g][kt] = v;
        }
        #pragma unroll
        for (int kf = 0; kf < 2; ++kf) {
            v4i v;
            #pragma unroll
            for (int d = 0; d < 4; ++d) {
                unsigned pw = 0;
                #pragma unroll
                for (int e = 0; e < 4; ++e) {
                    int qv = (int)__builtin_rintf(
                        Wg[g][(128 + kf * 64 + kq + d * 4 + e) * HH + un] * SW);
                    pw |= ((unsigned)(qv & 255)) << (8 * e);
                }
                v[d] = (int)pw;
            }
            wh[g][kf] = v;
        }
    }

    for (int i = tid; i < 2 * 2 * 192; i += 512)
        ((signed char*)hs8)[i] = 0;

    // ---- stage x chunk [0,16) ----
    {
        int cc = (tid >> 2) & 127, sq0 = tid & 3;
        const float* xp = x + ((size_t)bg0 * CC + cc) * TT + sq0 * 4;
        f32x4 v0 = *(const f32x4*)xp;
        f32x4 v1 = *(const f32x4*)(xp + (size_t)CC * TT);
        #pragma unroll
        for (int j = 0; j < 4; ++j) {
            xs[2 * (sq0 * 4 + j) + 0][cc] = f2bf(v0[j]);
            xs[2 * (sq0 * 4 + j) + 1][cc] = f2bf(v1[j]);
        }
    }
    __syncthreads();

    // x-part octet GEMM (bf16): m=16 tile = (8 steps x 2 batch), K=128.
    auto xzg = [&](int TB) {
        const int buf = (TB >> 3) & 1;
        f32x4 a2[4];
        #pragma unroll
        for (int g = 0; g < 4; ++g)
            a2[g] = (f32x4){bias[g], bias[g], bias[g], bias[g]};
        #pragma unroll
        for (int kt = 0; kt < 4; ++kt) {
            const int s = (TB + (l15 >> 1)) & 31;
            short8 a = *(const short8*)&xs[2 * s + (lane & 1)][kt * 32 + koff];
            #pragma unroll
            for (int g = 0; g < 4; ++g)
                a2[g] = __builtin_amdgcn_mfma_f32_16x16x32_bf16(a, wx[g][kt], a2[g], 0, 0, 0);
        }
        const int row0 = q << 2;              // D row = 2*dt + b
        #pragma unroll
        for (int r = 0; r < 4; ++r) {
            f32x4 vv = {a2[0][r], a2[1][r], a2[2][r], a2[3][r]};
            *(f32x4*)&xz[buf][row0 + r][un << 2] = vv;
        }
    };

    xzg(0);
    __syncthreads();

    // xz prefetch for t=0: this lane's gate-q scalar for b0 and b1
    const int cq4 = (un << 2) + q;
    float nxa = xz[0][0][cq4];
    float nxb = xz[0][1][cq4];

    float cst = 0.0f;                     // handler (lane<32) c-state
    f32x4 stg0 = {0, 0, 0, 0}, stg1 = {0, 0, 0, 0};
    float* outH = out;
    float* outC = out + (size_t)BB * HH * TT;
    const int scc = (tid >> 2) & 127, sq = tid & 3;
    const int fb = tid >> 8, fn = (tid >> 1) & 127, fh = tid & 1;

    for (int t = 0; t < TT; ++t) {
        const int p = t & 1;
        // ---- h-part MFMA: i8, i32 exact accumulation ----
        v4i a0 = *(const v4i*)&hs8[p][lane & 1][kq];
        v4i a1 = *(const v4i*)&hs8[p][lane & 1][64 + kq];
        v4i zi[4];
        #pragma unroll
        for (int g = 0; g < 4; ++g) {
            v4i ac = {0, 0, 0, 0};
            ac = __builtin_amdgcn_mfma_i32_16x16x64_i8(a0, wh[g][0], ac, 0, 0, 0);
            zi[g] = __builtin_amdgcn_mfma_i32_16x16x64_i8(a1, wh[g][1], ac, 0, 0, 0);
        }

        // ---- service (uniform branches) ----
        const int tm = t & 15;
        if (tm == 0) {
            if (t + 16 < TT) {
                const float* xp = x + ((size_t)bg0 * CC + scc) * TT + (t + 16) + sq * 4;
                stg0 = *(const f32x4*)xp;
                stg1 = *(const f32x4*)(xp + (size_t)CC * TT);
            }
        } else if (tm == 8) {
            if (t + 8 < TT) {
                #pragma unroll
                for (int j = 0; j < 4; ++j) {
                    int sl = (t + 8 + sq * 4 + j) & 31;
                    xs[2 * sl + 0][scc] = f2bf(stg0[j]);
                    xs[2 * sl + 1][scc] = f2bf(stg1[j]);
                }
            }
        }
        if ((t & 7) == 1 && t + 7 < TT)
            xzg(t + 7);
        if ((t & 31) == 12 && t >= 32) {
            const int ocp = (t >> 5) - 1;
            const unsigned short* hb = &hbuf[ocp & 1][fb][fn][fh * 16];
            float* op = outH + ((size_t)(bg0 + fb) * HH + fn) * TT + ocp * 32 + fh * 16;
            f32x4 o[4];
            #pragma unroll
            for (int j = 0; j < 16; ++j)
                o[j >> 2][j & 3] = bf2f(hb[j]);
            #pragma unroll
            for (int qq = 0; qq < 4; ++qq)
                *(f32x4*)(op + 4 * qq) = o[qq];
        }

        // ---- EW: quadrant q computes gate q's activation (all 64 lanes) ----
        // D quadrants identical: zi[g][0]=z[b0][l15], zi[g][1]=z[b1][l15].
        {
            float xa = nxa, xb = nxb;
            const int t1 = t + 1;
            const int buf1 = (t1 >> 3) & 1, dt1 = t1 & 7;
            nxa = xz[buf1][2 * dt1 + 0][cq4];
            nxb = xz[buf1][2 * dt1 + 1][cq4];

            int zs0 = (q & 2) ? ((q & 1) ? zi[3][0] : zi[2][0])
                              : ((q & 1) ? zi[1][0] : zi[0][0]);
            int zs1 = (q & 2) ? ((q & 1) ? zi[3][1] : zi[2][1])
                              : ((q & 1) ? zi[1][1] : zi[0][1]);
            float z0 = (float)zs0 * INV_SHW + xa;
            float z1 = (float)zs1 * INV_SHW + xb;
            float ya = ym * __builtin_amdgcn_rcpf(
                           1.0f + __builtin_amdgcn_exp2f(esc * z0)) + yk;
            float yb = ym * __builtin_amdgcn_rcpf(
                           1.0f + __builtin_amdgcn_exp2f(esc * z1)) + yk;
            ew[wid][l15][q]     = ya;
            ew[wid][l15][4 + q] = yb;
        }
        // handlers: lanes 0-31, (b = lane>>4, unit = un)
        if (lane < 32) {
            const int hbx = lane >> 4;
            f32x4 g4 = *(const f32x4*)&ew[wid][l15][hbx * 4];   // f,i,u,o
            cst = cst * g4[0] + g4[1] * g4[2];
            float th = 2.0f * __builtin_amdgcn_rcpf(
                           1.0f + __builtin_amdgcn_exp2f(-2.885390082f * cst)) - 1.0f;
            float h = g4[3] * th;
            hs8[p ^ 1][hbx][un] = (signed char)(int)__builtin_rintf(h * SH);
            hbuf[(t >> 5) & 1][hbx][un][t & 31] = f2bf(h);
        }
        BAR();
    }

    // ---- final flush: chunk 15 ----
    {
        const unsigned short* hb = &hbuf[1][fb][fn][fh * 16];
        float* op = outH + ((size_t)(bg0 + fb) * HH + fn) * TT + 480 + fh * 16;
        f32x4 o[4];
        #pragma unroll
        for (int j = 0; j < 16; ++j)
            o[j >> 2][j & 3] = bf2f(hb[j]);
        #pragma unroll
        for (int qq = 0; qq < 4; ++qq)
            *(f32x4*)(op + 4 * qq) = o[qq];
    }
    if (lane < 32)
        outC[(size_t)(bg0 + (lane >> 4)) * HH + un] = cst;
}

extern "C" void kernel_launch(void* const* d_in, const int* in_sizes, int n_in,
                              void* d_out, int out_size, void* d_ws, size_t ws_size,
                              hipStream_t stream) {
    const float* x  = (const float*)d_in[0];
    const float* Wf = (const float*)d_in[1];
    const float* bf = (const float*)d_in[2];
    const float* Wi = (const float*)d_in[3];
    const float* bi = (const float*)d_in[4];
    const float* Wu = (const float*)d_in[5];
    const float* bu = (const float*)d_in[6];
    const float* Wo = (const float*)d_in[7];
    const float* bo = (const float*)d_in[8];
    float* out = (float*)d_out;

    dim3 grid(BB / MB);   // 256 workgroups, 1 per CU
    dim3 block(512);      // 8 waves
    pclstm_kernel<<<grid, block, 0, stream>>>(x, Wf, bf, Wi, bi, Wu, bu, Wo, bo, out);
}